// Round 5
// baseline (249.891 us; speedup 1.0000x reference)
//
#include <hip/hip_runtime.h>

// PointTransformerLayer fused kernel (MI355X / gfx950) — round 15
//
// Math:
//   relu1 = relu(aI_i - a_j)            aI = pos@pW1 + pb1, a = pos@pW1
//   S1    = relu1 @ W_pa  +  QA_i  +  KNA_j  + c      (NEW: decomposed)
//     where W_pa = pW2@aW1 (K=64 MFMA),  QA_i = q_i@aW1  (f32, per-block
//     fold into creg),  KNA_j = (-k_j)@aW1  (f32 table knat[t][j], loaded
//     per tile and added to the accumulator),  c = ab1 + pb2@aW1.
//   H     = relu(S1);  simL2 = H @ (aW2*log2e)   (ab2 softmax-invariant)
//   rpe   = relu1 @ pW2 ; vv = (v+pb2)_j + rpe   (v folded into G3 C-op)
//   out_i[d] = sum_j 2^simL2 * vv / sum_j 2^simL2
//
// R15 = R14 (120.6us; G2 software-pipelined) + G1 K=128 -> K=64:
//   the (q_i - k_j)@aW1 half of G1 is bilinear (no relu in between), so it
//   is precomputed: per wave-iter MFMAs 40 -> 24, G1 chains 4-deep -> 2-deep,
//   A-frag LDS traffic and builder VALU halved (qI/kN arrays deleted),
//   Bf frags 16 -> 8 (-32 permanent VGPR).  The qk term moves bf16 -> f32
//   (strictly more accurate).  R12/R13 proved occupancy can't be bought with
//   launch bounds (spills); this attacks the latency-bound core directly.

typedef float f32x4 __attribute__((ext_vector_type(4)));
typedef int   i32x8 __attribute__((ext_vector_type(8)));
using sh8 = __attribute__((ext_vector_type(8))) short;  // 8 bf16 (4 VGPRs)

static constexpr int NPTS = 1024;

#if __has_builtin(__builtin_amdgcn_exp2f)
#define EXP2(x) __builtin_amdgcn_exp2f(x)
#else
#define EXP2(x) exp2f(x)
#endif

// ---- ws layout (bytes) ----
static constexpr size_t BEXT_OFF = 0;        // W_pa frags: 2*16*64*8 bf16 = 32768 B (kc<2 only)
static constexpr size_t AW2F_OFF = 65536;    // fp8 frags: 16384 B
static constexpr size_t PW2F_OFF = 81920;    // 8192 B
static constexpr size_t CARR_OFF = 90112;    // 256 f32 = 1024 B
static constexpr size_t AI_OFF   = 91136;    // 1024*64 f32 (+pb1)      = 262144 B
static constexpr size_t AJ_OFF   = 353280;   // 1024*64 bf16            = 131072 B
static constexpr size_t VPT_OFF  = 484352;   // 64*1024 f32 (v+pb2, T)  = 262144 B
static constexpr size_t QA_OFF   = 746496;   // 1024*256 f32 (q@aW1)    = 1048576 B
static constexpr size_t KNAT_OFF = 1795072;  // 256*1024 f32 ((-k)@aW1, t-major)

__device__ __forceinline__ unsigned short f2b_rne(float f) {
    unsigned u = __float_as_uint(f);
    u += 0x7fffu + ((u >> 16) & 1u);
    return (unsigned short)(u >> 16);
}
// trunc-pack two f32 into bf16x2 — single v_perm_b32
__device__ __forceinline__ unsigned pk2(float lo, float hi) {
    return __builtin_amdgcn_perm(__float_as_uint(hi), __float_as_uint(lo), 0x07060302);
}
__device__ __forceinline__ float b2f(unsigned short s) {
    return __uint_as_float(((unsigned)s) << 16);
}
__device__ __forceinline__ unsigned char f2fp8(float v) {
    return (unsigned char)(__builtin_amdgcn_cvt_pk_fp8_f32(v, 0.f, 0, false) & 0xff);
}
__device__ __forceinline__ unsigned pk4fp8(float a, float b, float c, float d) {
    int r = __builtin_amdgcn_cvt_pk_fp8_f32(a, b, 0, false);
    r = __builtin_amdgcn_cvt_pk_fp8_f32(c, d, r, true);
    return (unsigned)r;
}
__device__ __forceinline__ i32x8 ld32B(const void* p) {
    const uint4 a = ((const uint4*)p)[0];
    const uint4 b = ((const uint4*)p)[1];
    i32x8 r;
    r[0] = a.x; r[1] = a.y; r[2] = a.z; r[3] = a.w;
    r[4] = b.x; r[5] = b.y; r[6] = b.z; r[7] = b.w;
    return r;
}

// ---------------- combined prep ----------------
// blocks: [0,64) bextf(W_pa) | [64,128) aw2f8 | [128,144) pw2f | 144 cArr
//         [145,401) points (v, aI, aJ; 4/blk) | [401,1425) QA (1 i/blk)
//         [1425,1681) KNAT (4 j/blk)
__global__ void prep_all(const float* __restrict__ x, const float* __restrict__ pos,
                         const float* __restrict__ Wq, const float* __restrict__ Wk,
                         const float* __restrict__ Wv, const float* __restrict__ pW1,
                         const float* __restrict__ pb1, const float* __restrict__ pW2,
                         const float* __restrict__ pb2, const float* __restrict__ aW1,
                         const float* __restrict__ ab1, const float* __restrict__ aW2,
                         unsigned short* __restrict__ bextf, unsigned char* __restrict__ aw2f8,
                         unsigned short* __restrict__ pw2f, float* __restrict__ cArr,
                         float* __restrict__ vPT, float* __restrict__ aI,
                         unsigned short* __restrict__ aJ, float* __restrict__ qa,
                         float* __restrict__ knat)
{
    __shared__ float s1[4][64];
    __shared__ float s2[4][64];
    const int b = blockIdx.x;
    if (b < 64) {
        // W_pa = pW2@aW1 frags, kc<2 (R2-verified layout)
        const int idx = b * 256 + threadIdx.x;  // < 16384
        const int k = idx >> 8, t = idx & 255;
        float s = 0.f;
        for (int d = 0; d < 64; ++d) s = fmaf(pW2[k * 64 + d], aW1[d * 256 + t], s);
        const int kc = k >> 5, kl = k & 31, qq = kl >> 3, e = kl & 7;
        const int ntg = t >> 4, tl = t & 15;
        bextf[(((size_t)(kc * 16 + ntg) * 64) + (qq * 16 + tl)) * 8 + e] = f2b_rne(s);
    } else if (b < 128) {
        // aW2*log2e fp8 frags for mfma_scale 16x16x128 (R9-verified)
        const int r = (b - 64) * 256 + threadIdx.x;  // < 16384
        const int e = r & 31, lane = (r >> 5) & 63, wsl = (r >> 11) & 3, kb = r >> 13;
        const int q = lane >> 4, dl = lane & 15;
        const int kp = kb * 128 + q * 32 + e;
        const int t = 64 * (kp >> 6) + 16 * (kp & 3) + ((kp >> 2) & 15);
        const int d = 16 * wsl + dl;
        aw2f8[r] = f2fp8(aW2[t * 64 + d] * 1.4426950408889634f);
    } else if (b < 144) {
        // pW2 frags (R2-verified)
        const int r = (b - 128) * 256 + threadIdx.x;  // < 4096
        const int k = r >> 6, d = r & 63;
        const int kc = k >> 5, kl = k & 31, qq = kl >> 3, e = kl & 7;
        const int nt = d >> 4, dl = d & 15;
        pw2f[(((size_t)(kc * 4 + nt) * 64) + (qq * 16 + dl)) * 8 + e] = f2b_rne(pW2[k * 64 + d]);
    } else if (b == 144) {
        const int t = threadIdx.x;
        float s = ab1[t];
        for (int d = 0; d < 64; ++d) s = fmaf(pb2[d], aW1[d * 256 + t], s);
        cArr[t] = s;
    } else if (b < 401) {
        // per-point prep: v, aI, aJ — 4 points per block
        const int t = threadIdx.x, sub = t >> 6, d = t & 63;
        const int i = (b - 145) * 4 + sub;
        s1[sub][d] = x[i * 64 + d];
        __syncthreads();
        float v = 0.f;
        for (int e = 0; e < 64; ++e) v = fmaf(s1[sub][e], Wv[e * 64 + d], v);
        const float a = pos[i * 2] * pW1[d] + pos[i * 2 + 1] * pW1[64 + d];
        vPT[d * NPTS + i] = v + pb2[d];
        aI[i * 64 + d] = a + pb1[d];
        aJ[i * 64 + d] = f2b_rne(a);
    } else if (b < 1425) {
        // QA[i][t] = (x_i@Wq)@aW1, f32
        const int i = b - 401, t = threadIdx.x;
        if (t < 64) s1[0][t] = x[i * 64 + t];
        __syncthreads();
        if (t < 64) {
            float s = 0.f;
            for (int e = 0; e < 64; ++e) s = fmaf(s1[0][e], Wq[e * 64 + t], s);
            s2[0][t] = s;
        }
        __syncthreads();
        float s = 0.f;
        for (int d = 0; d < 64; ++d) s = fmaf(s2[0][d], aW1[d * 256 + t], s);
        qa[(size_t)i * 256 + t] = s;
    } else {
        // KNAT[t][j] = -(x_j@Wk)@aW1, t-major, 4 j per block (float4 writes)
        const int j0 = (b - 1425) * 4, t = threadIdx.x;
        const int jj = t >> 6, d = t & 63;
        s1[jj][d] = x[(j0 + jj) * 64 + d];
        __syncthreads();
        float s = 0.f;
        for (int e = 0; e < 64; ++e) s = fmaf(s1[jj][e], Wk[e * 64 + d], s);
        s2[jj][d] = s;
        __syncthreads();
        float r0 = 0.f, r1 = 0.f, r2 = 0.f, r3 = 0.f;
        for (int d2 = 0; d2 < 64; ++d2) {
            const float wv = aW1[d2 * 256 + t];
            r0 = fmaf(s2[0][d2], wv, r0);
            r1 = fmaf(s2[1][d2], wv, r1);
            r2 = fmaf(s2[2][d2], wv, r2);
            r3 = fmaf(s2[3][d2], wv, r3);
        }
        float4 o = {-r0, -r1, -r2, -r3};
        *(float4*)(knat + (size_t)t * NPTS + j0) = o;
    }
}

// ---------------- main fused kernel: one block per query i, j-tile 32 ----------------
__global__ __launch_bounds__(256, 2) void ptl_main(
    const float* __restrict__ aI, const unsigned short* __restrict__ aJ,
    const float* __restrict__ vPT,
    const unsigned short* __restrict__ bextf, const unsigned char* __restrict__ aw2f8,
    const unsigned short* __restrict__ pw2f, const float* __restrict__ cArr,
    const float* __restrict__ qa, const float* __restrict__ knat,
    float* __restrict__ out)
{
    const int i    = blockIdx.x;
    const int tid  = threadIdx.x;
    const int w    = tid >> 6;    // wave: t-slice [64w,64w+64) for G1, d-slice [16w,16w+16) for G2/G3
    const int lane = tid & 63;
    const int m    = lane & 15;
    const int q    = lane >> 4;

    // double-buffered LDS: AfL 8 KB + Hs 17 KB = 25 KB
    __shared__ __align__(16) uint4 AfL[2][2][2][64];              // [buf][sub][kc][lane]
    __shared__ __align__(16) unsigned char Hs[2][2][16 * 272];    // fp8 H, stride 272

    // constant B fragments
    sh8 Bf[8];  // G1 (W_pa): [kc 0..1][nt 0..3]
#pragma unroll
    for (int kc = 0; kc < 2; ++kc)
#pragma unroll
        for (int nt = 0; nt < 4; ++nt)
            Bf[kc * 4 + nt] = *(const sh8*)(bextf + ((size_t)((kc * 16 + 4 * w + nt) * 64 + lane)) * 8);
    i32x8 W2f[2];  // G2 fp8: [kb 0..1], d-slice w
#pragma unroll
    for (int kb = 0; kb < 2; ++kb)
        W2f[kb] = ld32B(aw2f8 + ((size_t)((kb * 4 + w) * 64 + lane)) * 32);
    sh8 P2f[2];  // G3: [kc 0..1], d-slice w
#pragma unroll
    for (int kc = 0; kc < 2; ++kc)
        P2f[kc] = *(const sh8*)(pw2f + ((size_t)((kc * 4 + w) * 64 + lane)) * 8);

    float creg[4];  // c + QA_i  (both constant over j)
#pragma unroll
    for (int nt = 0; nt < 4; ++nt)
        creg[nt] = cArr[64 * w + 16 * nt + m] + qa[(size_t)i * 256 + 64 * w + 16 * nt + m];

    // builder: wave w builds A-frag (sub s_, k-half h_) of relu1
    const int s_ = w >> 1, h_ = w & 1;
    const unsigned short* bsrc  = aJ + m * 64 + h_ * 32 + q * 8;
    const float*          ibase = aI + i * 64 + h_ * 32 + q * 8;
    float iv[8];
    *(float4*)(iv)     = *(const float4*)(ibase);
    *(float4*)(iv + 4) = *(const float4*)(ibase + 4);

    // prologue: build this wave's task for tile 0 into buffer 0
    {
        const sh8 raw = *(const sh8*)(bsrc + (size_t)(16 * s_) * 64);
        float t[8];
#pragma unroll
        for (int e = 0; e < 8; ++e)
            t[e] = fmaxf(iv[e] - b2f((unsigned short)raw[e]), 0.f);
        uint4 pk;
        pk.x = pk2(t[0], t[1]); pk.y = pk2(t[2], t[3]);
        pk.z = pk2(t[4], t[5]); pk.w = pk2(t[6], t[7]);
        AfL[0][s_][h_][lane] = pk;
    }
    __syncthreads();

    float num = 0.f, den = 0.f;
    const f32x4 z4 = {0.f, 0.f, 0.f, 0.f};
    f32x4 aRp0 = z4, aRp1 = z4;   // previous tile's G3 results (pipeline carry)
    const float* vbase  = vPT + (size_t)(16 * w + m) * NPTS;
    const float* knbase = knat + (size_t)(64 * w + m) * NPTS;

    for (int n = 0; n < 32; ++n) {
        const int pb = n & 1, nb = pb ^ 1;
        const int j0 = n << 5;

        // next tile's raw global load (this wave's single task), issued early
        sh8 rawN;
        if (n < 31) rawN = *(const sh8*)(bsrc + (size_t)(j0 + 32 + 16 * s_) * 64);
        // v values for own tile (C-operand of G3)
        const float4 vj0 = *(const float4*)(vbase + j0 + 4 * q);
        const float4 vj1 = *(const float4*)(vbase + j0 + 16 + 4 * q);
        // KNA for sub0 rows (f32, added to acc post-MFMA)
        f32x4 ka0[4];
#pragma unroll
        for (int nt = 0; nt < 4; ++nt)
            ka0[nt] = *(const f32x4*)(knbase + (size_t)nt * 16 * NPTS + j0 + 4 * q);

        // ---- A-frags (relu1 only now: 4 b128 reads) ----
        const sh8 A00 = *(const sh8*)&AfL[pb][0][0][lane];
        const sh8 A01 = *(const sh8*)&AfL[pb][0][1][lane];
        const sh8 A10 = *(const sh8*)&AfL[pb][1][0][lane];
        const sh8 A11 = *(const sh8*)&AfL[pb][1][1][lane];

        // ---- sub 0: G1 (K=64) + KNA add + H-write (fp8 pack) ----
        {
            f32x4 acc[4];
#pragma unroll
            for (int nt = 0; nt < 4; ++nt) {
                const f32x4 cv = {creg[nt], creg[nt], creg[nt], creg[nt]};
                acc[nt] = __builtin_amdgcn_mfma_f32_16x16x32_bf16(A00, Bf[0 * 4 + nt], cv, 0, 0, 0);
                acc[nt] = __builtin_amdgcn_mfma_f32_16x16x32_bf16(A01, Bf[1 * 4 + nt], acc[nt], 0, 0, 0);
                acc[nt] = acc[nt] + ka0[nt];
            }
            unsigned char* hw = Hs[pb][0] + (4 * q) * 272 + 64 * w + 4 * m;
#pragma unroll
            for (int r = 0; r < 4; ++r)
                *(unsigned*)(hw + r * 272) = pk4fp8(fmaxf(acc[0][r], 0.f), fmaxf(acc[1][r], 0.f),
                                                   fmaxf(acc[2][r], 0.f), fmaxf(acc[3][r], 0.f));
        }

        // KNA for sub1 rows (issued after sub0 pack; covered by sub1 MFMAs)
        f32x4 ka1[4];
#pragma unroll
        for (int nt = 0; nt < 4; ++nt)
            ka1[nt] = *(const f32x4*)(knbase + (size_t)nt * 16 * NPTS + j0 + 16 + 4 * q);

        // ---- deferred-G2 LDS loads for tile n-1 (Hs[nb], published last barrier) ----
        i32x8 h00, h01, h10, h11;
        if (n) {
            h00 = ld32B(Hs[nb][0] + m * 272 + 0   + 32 * q);
            h01 = ld32B(Hs[nb][0] + m * 272 + 128 + 32 * q);
            h10 = ld32B(Hs[nb][1] + m * 272 + 0   + 32 * q);
            h11 = ld32B(Hs[nb][1] + m * 272 + 128 + 32 * q);
        }

        // ---- sub 1: G1 + KNA add + H-write ----
        {
            f32x4 acc[4];
#pragma unroll
            for (int nt = 0; nt < 4; ++nt) {
                const f32x4 cv = {creg[nt], creg[nt], creg[nt], creg[nt]};
                acc[nt] = __builtin_amdgcn_mfma_f32_16x16x32_bf16(A10, Bf[0 * 4 + nt], cv, 0, 0, 0);
                acc[nt] = __builtin_amdgcn_mfma_f32_16x16x32_bf16(A11, Bf[1 * 4 + nt], acc[nt], 0, 0, 0);
                acc[nt] = acc[nt] + ka1[nt];
            }
            unsigned char* hw = Hs[pb][1] + (4 * q) * 272 + 64 * w + 4 * m;
#pragma unroll
            for (int r = 0; r < 4; ++r)
                *(unsigned*)(hw + r * 272) = pk4fp8(fmaxf(acc[0][r], 0.f), fmaxf(acc[1][r], 0.f),
                                                   fmaxf(acc[2][r], 0.f), fmaxf(acc[3][r], 0.f));
        }

        // ---- deferred G2 for tile n-1: simL2 + softmax accumulation ----
        if (n) {
            f32x4 aS0 = z4, aS1 = z4;
            aS0 = __builtin_amdgcn_mfma_scale_f32_16x16x128_f8f6f4(
                h00, W2f[0], aS0, 0, 0, 0, 127, 0, 127);
            aS0 = __builtin_amdgcn_mfma_scale_f32_16x16x128_f8f6f4(
                h01, W2f[1], aS0, 0, 0, 0, 127, 0, 127);
            aS1 = __builtin_amdgcn_mfma_scale_f32_16x16x128_f8f6f4(
                h10, W2f[0], aS1, 0, 0, 0, 127, 0, 127);
            aS1 = __builtin_amdgcn_mfma_scale_f32_16x16x128_f8f6f4(
                h11, W2f[1], aS1, 0, 0, 0, 127, 0, 127);
#pragma unroll
            for (int r = 0; r < 4; ++r) {
                const float e0 = EXP2(aS0[r]);
                num = fmaf(e0, aRp0[r], num);
                den += e0;
                const float e1 = EXP2(aS1[r]);
                num = fmaf(e1, aRp1[r], num);
                den += e1;
            }
        }

        // ---- G3 (pre-barrier): rpe + v for tile n, aR carried to iter n+1 ----
        const f32x4 vc0 = {vj0.x, vj0.y, vj0.z, vj0.w};
        const f32x4 vc1 = {vj1.x, vj1.y, vj1.z, vj1.w};
        f32x4 aR0 = __builtin_amdgcn_mfma_f32_16x16x32_bf16(A00, P2f[0], vc0, 0, 0, 0);
        aR0 = __builtin_amdgcn_mfma_f32_16x16x32_bf16(A01, P2f[1], aR0, 0, 0, 0);
        f32x4 aR1 = __builtin_amdgcn_mfma_f32_16x16x32_bf16(A10, P2f[0], vc1, 0, 0, 0);
        aR1 = __builtin_amdgcn_mfma_f32_16x16x32_bf16(A11, P2f[1], aR1, 0, 0, 0);
        aRp0 = aR0;
        aRp1 = aR1;

        // build next tile's A-frag (this wave's single task)
        if (n < 31) {
            float t[8];
#pragma unroll
            for (int e = 0; e < 8; ++e)
                t[e] = fmaxf(iv[e] - b2f((unsigned short)rawN[e]), 0.f);
            uint4 pk;
            pk.x = pk2(t[0], t[1]); pk.y = pk2(t[2], t[3]);
            pk.z = pk2(t[4], t[5]); pk.w = pk2(t[6], t[7]);
            AfL[nb][s_][h_][lane] = pk;
        }

        __syncthreads();  // publishes Hs[pb][*] (G2 next iter) and AfL[nb][*]
    }

    // ---- epilogue: deferred G2 for the final tile (pb=1, published above) ----
    {
        f32x4 aS0 = z4, aS1 = z4;
        const i32x8 h00 = ld32B(Hs[1][0] + m * 272 + 0   + 32 * q);
        const i32x8 h01 = ld32B(Hs[1][0] + m * 272 + 128 + 32 * q);
        const i32x8 h10 = ld32B(Hs[1][1] + m * 272 + 0   + 32 * q);
        const i32x8 h11 = ld32B(Hs[1][1] + m * 272 + 128 + 32 * q);
        aS0 = __builtin_amdgcn_mfma_scale_f32_16x16x128_f8f6f4(
            h00, W2f[0], aS0, 0, 0, 0, 127, 0, 127);
        aS0 = __builtin_amdgcn_mfma_scale_f32_16x16x128_f8f6f4(
            h01, W2f[1], aS0, 0, 0, 0, 127, 0, 127);
        aS1 = __builtin_amdgcn_mfma_scale_f32_16x16x128_f8f6f4(
            h10, W2f[0], aS1, 0, 0, 0, 127, 0, 127);
        aS1 = __builtin_amdgcn_mfma_scale_f32_16x16x128_f8f6f4(
            h11, W2f[1], aS1, 0, 0, 0, 127, 0, 127);
#pragma unroll
        for (int r = 0; r < 4; ++r) {
            const float e0 = EXP2(aS0[r]);
            num = fmaf(e0, aRp0[r], num);
            den += e0;
            const float e1 = EXP2(aS1[r]);
            num = fmaf(e1, aRp1[r], num);
            den += e1;
        }
    }

    // reduce the 4 quad-partials (lanes m, m+16, m+32, m+48)
    num += __shfl_xor(num, 16);
    num += __shfl_xor(num, 32);
    den += __shfl_xor(den, 16);
    den += __shfl_xor(den, 32);
    if (q == 0) out[i * 64 + 16 * w + m] = num / den;
}

extern "C" void kernel_launch(void* const* d_in, const int* in_sizes, int n_in,
                              void* d_out, int out_size, void* d_ws, size_t ws_size,
                              hipStream_t stream) {
    const float* x   = (const float*)d_in[0];
    const float* pos = (const float*)d_in[1];
    const float* Wq  = (const float*)d_in[2];
    const float* Wk  = (const float*)d_in[3];
    const float* Wv  = (const float*)d_in[4];
    const float* pW1 = (const float*)d_in[5];
    const float* pb1 = (const float*)d_in[6];
    const float* pW2 = (const float*)d_in[7];
    const float* pb2 = (const float*)d_in[8];
    const float* aW1 = (const float*)d_in[9];
    const float* ab1 = (const float*)d_in[10];
    const float* aW2 = (const float*)d_in[11];
    // d_in[12] = ab2: constant over j -> cancels in per-channel softmax, unused.

    char* ws = (char*)d_ws;
    unsigned short* bextf = (unsigned short*)(ws + BEXT_OFF);
    unsigned char*  aw2f8 = (unsigned char*)(ws + AW2F_OFF);
    unsigned short* pw2f  = (unsigned short*)(ws + PW2F_OFF);
    float*          cArr  = (float*)(ws + CARR_OFF);
    float*          aIa   = (float*)(ws + AI_OFF);
    unsigned short* aJa   = (unsigned short*)(ws + AJ_OFF);
    float*          vPTa  = (float*)(ws + VPT_OFF);
    float*          qaA   = (float*)(ws + QA_OFF);
    float*          knatA = (float*)(ws + KNAT_OFF);

    prep_all<<<1681, 256, 0, stream>>>(x, pos, Wq, Wk, Wv, pW1, pb1, pW2, pb2, aW1, ab1, aW2,
                                       bextf, aw2f8, pw2f, cArr, vPTa, aIa, aJa, qaA, knatA);
    ptl_main<<<NPTS, 256, 0, stream>>>(aIa, aJa, vPTa, bextf, aw2f8, pw2f, cArr, qaA, knatA,
                                       (float*)d_out);
}

// Round 6
// 242.671 us; speedup vs baseline: 1.0298x; 1.0298x over previous
//
#include <hip/hip_runtime.h>

// PointTransformerLayer fused kernel (MI355X / gfx950) — round 16
//
// Math:
//   relu1 = relu(aI_i - a_j)            aI = pos@pW1 + pb1, a = pos@pW1
//   S1    = relu1 @ W_pa  +  QA_i  +  KNA_j  + c      (decomposed, R15)
//     where W_pa = pW2@aW1 (K=64 MFMA),  QA_i = q_i@aW1  (f32, folded
//     into creg),  KNA_j = (-k_j)@aW1  (f32 table knat[t][j], prefetched),
//     c = ab1 + pb2@aW1.
//   H     = relu(S1);  simL2 = H @ (aW2*log2e)   (ab2 softmax-invariant)
//   rpe   = relu1 @ pW2 ; vv = (v+pb2)_j + rpe   (v folded into G3 C-op)
//   out_i[d] = sum_j 2^simL2 * vv / sum_j 2^simL2
//
// R16 = R15 + ka SOFTWARE PREFETCH (one tile ahead, same registers):
//   R15 regressed 120.6 -> 181us because ka0 (global/L2, ~300-500cy) was
//   issued at the top of the iteration and consumed ~150cy later -> every
//   wave stalled every iteration (MfmaUtil 33 -> 13.6, VALU 53 -> 24, the
//   pure-latency-stall signature; the 24-MFMA work model itself verified:
//   13.6% x 181us = 24.6us of MFMA pipe, exactly as designed).
//   Fix: consume ka for tile n early, reload the SAME registers for tile
//   n+1 right after last use — G2 + G3 + builder + barrier + next iter's
//   A-frag reads + 8 MFMAs (~1500cy) cover the latency.  Pure code motion;
//   math bit-identical to R15 (absmax 0.0625).

typedef float f32x4 __attribute__((ext_vector_type(4)));
typedef int   i32x8 __attribute__((ext_vector_type(8)));
using sh8 = __attribute__((ext_vector_type(8))) short;  // 8 bf16 (4 VGPRs)

static constexpr int NPTS = 1024;

#if __has_builtin(__builtin_amdgcn_exp2f)
#define EXP2(x) __builtin_amdgcn_exp2f(x)
#else
#define EXP2(x) exp2f(x)
#endif

// ---- ws layout (bytes) ----
static constexpr size_t BEXT_OFF = 0;        // W_pa frags: 2*16*64*8 bf16 = 32768 B (kc<2 only)
static constexpr size_t AW2F_OFF = 65536;    // fp8 frags: 16384 B
static constexpr size_t PW2F_OFF = 81920;    // 8192 B
static constexpr size_t CARR_OFF = 90112;    // 256 f32 = 1024 B
static constexpr size_t AI_OFF   = 91136;    // 1024*64 f32 (+pb1)      = 262144 B
static constexpr size_t AJ_OFF   = 353280;   // 1024*64 bf16            = 131072 B
static constexpr size_t VPT_OFF  = 484352;   // 64*1024 f32 (v+pb2, T)  = 262144 B
static constexpr size_t QA_OFF   = 746496;   // 1024*256 f32 (q@aW1)    = 1048576 B
static constexpr size_t KNAT_OFF = 1795072;  // 256*1024 f32 ((-k)@aW1, t-major)

__device__ __forceinline__ unsigned short f2b_rne(float f) {
    unsigned u = __float_as_uint(f);
    u += 0x7fffu + ((u >> 16) & 1u);
    return (unsigned short)(u >> 16);
}
// trunc-pack two f32 into bf16x2 — single v_perm_b32
__device__ __forceinline__ unsigned pk2(float lo, float hi) {
    return __builtin_amdgcn_perm(__float_as_uint(hi), __float_as_uint(lo), 0x07060302);
}
__device__ __forceinline__ float b2f(unsigned short s) {
    return __uint_as_float(((unsigned)s) << 16);
}
__device__ __forceinline__ unsigned char f2fp8(float v) {
    return (unsigned char)(__builtin_amdgcn_cvt_pk_fp8_f32(v, 0.f, 0, false) & 0xff);
}
__device__ __forceinline__ unsigned pk4fp8(float a, float b, float c, float d) {
    int r = __builtin_amdgcn_cvt_pk_fp8_f32(a, b, 0, false);
    r = __builtin_amdgcn_cvt_pk_fp8_f32(c, d, r, true);
    return (unsigned)r;
}
__device__ __forceinline__ i32x8 ld32B(const void* p) {
    const uint4 a = ((const uint4*)p)[0];
    const uint4 b = ((const uint4*)p)[1];
    i32x8 r;
    r[0] = a.x; r[1] = a.y; r[2] = a.z; r[3] = a.w;
    r[4] = b.x; r[5] = b.y; r[6] = b.z; r[7] = b.w;
    return r;
}

// ---------------- combined prep ----------------
// blocks: [0,64) bextf(W_pa) | [64,128) aw2f8 | [128,144) pw2f | 144 cArr
//         [145,401) points (v, aI, aJ; 4/blk) | [401,1425) QA (1 i/blk)
//         [1425,1681) KNAT (4 j/blk)
__global__ void prep_all(const float* __restrict__ x, const float* __restrict__ pos,
                         const float* __restrict__ Wq, const float* __restrict__ Wk,
                         const float* __restrict__ Wv, const float* __restrict__ pW1,
                         const float* __restrict__ pb1, const float* __restrict__ pW2,
                         const float* __restrict__ pb2, const float* __restrict__ aW1,
                         const float* __restrict__ ab1, const float* __restrict__ aW2,
                         unsigned short* __restrict__ bextf, unsigned char* __restrict__ aw2f8,
                         unsigned short* __restrict__ pw2f, float* __restrict__ cArr,
                         float* __restrict__ vPT, float* __restrict__ aI,
                         unsigned short* __restrict__ aJ, float* __restrict__ qa,
                         float* __restrict__ knat)
{
    __shared__ float s1[4][64];
    __shared__ float s2[4][64];
    const int b = blockIdx.x;
    if (b < 64) {
        // W_pa = pW2@aW1 frags, kc<2 (R2-verified layout)
        const int idx = b * 256 + threadIdx.x;  // < 16384
        const int k = idx >> 8, t = idx & 255;
        float s = 0.f;
        for (int d = 0; d < 64; ++d) s = fmaf(pW2[k * 64 + d], aW1[d * 256 + t], s);
        const int kc = k >> 5, kl = k & 31, qq = kl >> 3, e = kl & 7;
        const int ntg = t >> 4, tl = t & 15;
        bextf[(((size_t)(kc * 16 + ntg) * 64) + (qq * 16 + tl)) * 8 + e] = f2b_rne(s);
    } else if (b < 128) {
        // aW2*log2e fp8 frags for mfma_scale 16x16x128 (R9-verified)
        const int r = (b - 64) * 256 + threadIdx.x;  // < 16384
        const int e = r & 31, lane = (r >> 5) & 63, wsl = (r >> 11) & 3, kb = r >> 13;
        const int q = lane >> 4, dl = lane & 15;
        const int kp = kb * 128 + q * 32 + e;
        const int t = 64 * (kp >> 6) + 16 * (kp & 3) + ((kp >> 2) & 15);
        const int d = 16 * wsl + dl;
        aw2f8[r] = f2fp8(aW2[t * 64 + d] * 1.4426950408889634f);
    } else if (b < 144) {
        // pW2 frags (R2-verified)
        const int r = (b - 128) * 256 + threadIdx.x;  // < 4096
        const int k = r >> 6, d = r & 63;
        const int kc = k >> 5, kl = k & 31, qq = kl >> 3, e = kl & 7;
        const int nt = d >> 4, dl = d & 15;
        pw2f[(((size_t)(kc * 4 + nt) * 64) + (qq * 16 + dl)) * 8 + e] = f2b_rne(pW2[k * 64 + d]);
    } else if (b == 144) {
        const int t = threadIdx.x;
        float s = ab1[t];
        for (int d = 0; d < 64; ++d) s = fmaf(pb2[d], aW1[d * 256 + t], s);
        cArr[t] = s;
    } else if (b < 401) {
        // per-point prep: v, aI, aJ — 4 points per block
        const int t = threadIdx.x, sub = t >> 6, d = t & 63;
        const int i = (b - 145) * 4 + sub;
        s1[sub][d] = x[i * 64 + d];
        __syncthreads();
        float v = 0.f;
        for (int e = 0; e < 64; ++e) v = fmaf(s1[sub][e], Wv[e * 64 + d], v);
        const float a = pos[i * 2] * pW1[d] + pos[i * 2 + 1] * pW1[64 + d];
        vPT[d * NPTS + i] = v + pb2[d];
        aI[i * 64 + d] = a + pb1[d];
        aJ[i * 64 + d] = f2b_rne(a);
    } else if (b < 1425) {
        // QA[i][t] = (x_i@Wq)@aW1, f32
        const int i = b - 401, t = threadIdx.x;
        if (t < 64) s1[0][t] = x[i * 64 + t];
        __syncthreads();
        if (t < 64) {
            float s = 0.f;
            for (int e = 0; e < 64; ++e) s = fmaf(s1[0][e], Wq[e * 64 + t], s);
            s2[0][t] = s;
        }
        __syncthreads();
        float s = 0.f;
        for (int d = 0; d < 64; ++d) s = fmaf(s2[0][d], aW1[d * 256 + t], s);
        qa[(size_t)i * 256 + t] = s;
    } else {
        // KNAT[t][j] = -(x_j@Wk)@aW1, t-major, 4 j per block (float4 writes)
        const int j0 = (b - 1425) * 4, t = threadIdx.x;
        const int jj = t >> 6, d = t & 63;
        s1[jj][d] = x[(j0 + jj) * 64 + d];
        __syncthreads();
        float s = 0.f;
        for (int e = 0; e < 64; ++e) s = fmaf(s1[jj][e], Wk[e * 64 + d], s);
        s2[jj][d] = s;
        __syncthreads();
        float r0 = 0.f, r1 = 0.f, r2 = 0.f, r3 = 0.f;
        for (int d2 = 0; d2 < 64; ++d2) {
            const float wv = aW1[d2 * 256 + t];
            r0 = fmaf(s2[0][d2], wv, r0);
            r1 = fmaf(s2[1][d2], wv, r1);
            r2 = fmaf(s2[2][d2], wv, r2);
            r3 = fmaf(s2[3][d2], wv, r3);
        }
        float4 o = {-r0, -r1, -r2, -r3};
        *(float4*)(knat + (size_t)t * NPTS + j0) = o;
    }
}

// ---------------- main fused kernel: one block per query i, j-tile 32 ----------------
__global__ __launch_bounds__(256, 2) void ptl_main(
    const float* __restrict__ aI, const unsigned short* __restrict__ aJ,
    const float* __restrict__ vPT,
    const unsigned short* __restrict__ bextf, const unsigned char* __restrict__ aw2f8,
    const unsigned short* __restrict__ pw2f, const float* __restrict__ cArr,
    const float* __restrict__ qa, const float* __restrict__ knat,
    float* __restrict__ out)
{
    const int i    = blockIdx.x;
    const int tid  = threadIdx.x;
    const int w    = tid >> 6;    // wave: t-slice [64w,64w+64) for G1, d-slice [16w,16w+16) for G2/G3
    const int lane = tid & 63;
    const int m    = lane & 15;
    const int q    = lane >> 4;

    // double-buffered LDS: AfL 8 KB + Hs 17 KB = 25 KB
    __shared__ __align__(16) uint4 AfL[2][2][2][64];              // [buf][sub][kc][lane]
    __shared__ __align__(16) unsigned char Hs[2][2][16 * 272];    // fp8 H, stride 272

    // constant B fragments
    sh8 Bf[8];  // G1 (W_pa): [kc 0..1][nt 0..3]
#pragma unroll
    for (int kc = 0; kc < 2; ++kc)
#pragma unroll
        for (int nt = 0; nt < 4; ++nt)
            Bf[kc * 4 + nt] = *(const sh8*)(bextf + ((size_t)((kc * 16 + 4 * w + nt) * 64 + lane)) * 8);
    i32x8 W2f[2];  // G2 fp8: [kb 0..1], d-slice w
#pragma unroll
    for (int kb = 0; kb < 2; ++kb)
        W2f[kb] = ld32B(aw2f8 + ((size_t)((kb * 4 + w) * 64 + lane)) * 32);
    sh8 P2f[2];  // G3: [kc 0..1], d-slice w
#pragma unroll
    for (int kc = 0; kc < 2; ++kc)
        P2f[kc] = *(const sh8*)(pw2f + ((size_t)((kc * 4 + w) * 64 + lane)) * 8);

    float creg[4];  // c + QA_i  (both constant over j)
#pragma unroll
    for (int nt = 0; nt < 4; ++nt)
        creg[nt] = cArr[64 * w + 16 * nt + m] + qa[(size_t)i * 256 + 64 * w + 16 * nt + m];

    // builder: wave w builds A-frag (sub s_, k-half h_) of relu1
    const int s_ = w >> 1, h_ = w & 1;
    const unsigned short* bsrc  = aJ + m * 64 + h_ * 32 + q * 8;
    const float*          ibase = aI + i * 64 + h_ * 32 + q * 8;
    float iv[8];
    *(float4*)(iv)     = *(const float4*)(ibase);
    *(float4*)(iv + 4) = *(const float4*)(ibase + 4);

    const float* vbase  = vPT + (size_t)(16 * w + m) * NPTS;
    const float* knbase = knat + (size_t)(64 * w + m) * NPTS;

    // ka prefetch registers (tile 0 loaded in prologue; reloaded one tile
    // ahead inside the loop, right after last use — R16 fix)
    f32x4 ka0[4], ka1[4];
#pragma unroll
    for (int nt = 0; nt < 4; ++nt) {
        ka0[nt] = *(const f32x4*)(knbase + (size_t)nt * 16 * NPTS + 4 * q);
        ka1[nt] = *(const f32x4*)(knbase + (size_t)nt * 16 * NPTS + 16 + 4 * q);
    }

    // prologue: build this wave's task for tile 0 into buffer 0
    {
        const sh8 raw = *(const sh8*)(bsrc + (size_t)(16 * s_) * 64);
        float t[8];
#pragma unroll
        for (int e = 0; e < 8; ++e)
            t[e] = fmaxf(iv[e] - b2f((unsigned short)raw[e]), 0.f);
        uint4 pk;
        pk.x = pk2(t[0], t[1]); pk.y = pk2(t[2], t[3]);
        pk.z = pk2(t[4], t[5]); pk.w = pk2(t[6], t[7]);
        AfL[0][s_][h_][lane] = pk;
    }
    __syncthreads();

    float num = 0.f, den = 0.f;
    const f32x4 z4 = {0.f, 0.f, 0.f, 0.f};
    f32x4 aRp0 = z4, aRp1 = z4;   // previous tile's G3 results (pipeline carry)

    for (int n = 0; n < 32; ++n) {
        const int pb = n & 1, nb = pb ^ 1;
        const int j0 = n << 5;

        // next tile's raw global load (this wave's single task), issued early
        sh8 rawN;
        if (n < 31) rawN = *(const sh8*)(bsrc + (size_t)(j0 + 32 + 16 * s_) * 64);
        // v values for own tile (C-operand of G3)
        const float4 vj0 = *(const float4*)(vbase + j0 + 4 * q);
        const float4 vj1 = *(const float4*)(vbase + j0 + 16 + 4 * q);

        // ---- A-frags (relu1 only: 4 b128 reads) ----
        const sh8 A00 = *(const sh8*)&AfL[pb][0][0][lane];
        const sh8 A01 = *(const sh8*)&AfL[pb][0][1][lane];
        const sh8 A10 = *(const sh8*)&AfL[pb][1][0][lane];
        const sh8 A11 = *(const sh8*)&AfL[pb][1][1][lane];

        // ---- sub 0: G1 (K=64) + KNA add + H-write (fp8 pack) ----
        {
            f32x4 acc[4];
#pragma unroll
            for (int nt = 0; nt < 4; ++nt) {
                const f32x4 cv = {creg[nt], creg[nt], creg[nt], creg[nt]};
                acc[nt] = __builtin_amdgcn_mfma_f32_16x16x32_bf16(A00, Bf[0 * 4 + nt], cv, 0, 0, 0);
                acc[nt] = __builtin_amdgcn_mfma_f32_16x16x32_bf16(A01, Bf[1 * 4 + nt], acc[nt], 0, 0, 0);
                acc[nt] = acc[nt] + ka0[nt];
            }
            unsigned char* hw = Hs[pb][0] + (4 * q) * 272 + 64 * w + 4 * m;
#pragma unroll
            for (int r = 0; r < 4; ++r)
                *(unsigned*)(hw + r * 272) = pk4fp8(fmaxf(acc[0][r], 0.f), fmaxf(acc[1][r], 0.f),
                                                   fmaxf(acc[2][r], 0.f), fmaxf(acc[3][r], 0.f));
        }

        // ---- sub 1: G1 + KNA add + H-write ----
        {
            f32x4 acc[4];
#pragma unroll
            for (int nt = 0; nt < 4; ++nt) {
                const f32x4 cv = {creg[nt], creg[nt], creg[nt], creg[nt]};
                acc[nt] = __builtin_amdgcn_mfma_f32_16x16x32_bf16(A10, Bf[0 * 4 + nt], cv, 0, 0, 0);
                acc[nt] = __builtin_amdgcn_mfma_f32_16x16x32_bf16(A11, Bf[1 * 4 + nt], acc[nt], 0, 0, 0);
                acc[nt] = acc[nt] + ka1[nt];
            }
            unsigned char* hw = Hs[pb][1] + (4 * q) * 272 + 64 * w + 4 * m;
#pragma unroll
            for (int r = 0; r < 4; ++r)
                *(unsigned*)(hw + r * 272) = pk4fp8(fmaxf(acc[0][r], 0.f), fmaxf(acc[1][r], 0.f),
                                                   fmaxf(acc[2][r], 0.f), fmaxf(acc[3][r], 0.f));
        }

        // ---- ka RELOAD for tile n+1 (same registers, right after last use);
        //      covered by G2 + G3 + builder + barrier + next iter's G1 ----
        if (n < 31) {
#pragma unroll
            for (int nt = 0; nt < 4; ++nt) {
                ka0[nt] = *(const f32x4*)(knbase + (size_t)nt * 16 * NPTS + j0 + 32 + 4 * q);
                ka1[nt] = *(const f32x4*)(knbase + (size_t)nt * 16 * NPTS + j0 + 48 + 4 * q);
            }
        }

        // ---- deferred-G2 LDS loads for tile n-1 (Hs[nb], published last barrier) ----
        i32x8 h00, h01, h10, h11;
        if (n) {
            h00 = ld32B(Hs[nb][0] + m * 272 + 0   + 32 * q);
            h01 = ld32B(Hs[nb][0] + m * 272 + 128 + 32 * q);
            h10 = ld32B(Hs[nb][1] + m * 272 + 0   + 32 * q);
            h11 = ld32B(Hs[nb][1] + m * 272 + 128 + 32 * q);
        }

        // ---- deferred G2 for tile n-1: simL2 + softmax accumulation ----
        if (n) {
            f32x4 aS0 = z4, aS1 = z4;
            aS0 = __builtin_amdgcn_mfma_scale_f32_16x16x128_f8f6f4(
                h00, W2f[0], aS0, 0, 0, 0, 127, 0, 127);
            aS0 = __builtin_amdgcn_mfma_scale_f32_16x16x128_f8f6f4(
                h01, W2f[1], aS0, 0, 0, 0, 127, 0, 127);
            aS1 = __builtin_amdgcn_mfma_scale_f32_16x16x128_f8f6f4(
                h10, W2f[0], aS1, 0, 0, 0, 127, 0, 127);
            aS1 = __builtin_amdgcn_mfma_scale_f32_16x16x128_f8f6f4(
                h11, W2f[1], aS1, 0, 0, 0, 127, 0, 127);
#pragma unroll
            for (int r = 0; r < 4; ++r) {
                const float e0 = EXP2(aS0[r]);
                num = fmaf(e0, aRp0[r], num);
                den += e0;
                const float e1 = EXP2(aS1[r]);
                num = fmaf(e1, aRp1[r], num);
                den += e1;
            }
        }

        // ---- G3 (pre-barrier): rpe + v for tile n, aR carried to iter n+1 ----
        const f32x4 vc0 = {vj0.x, vj0.y, vj0.z, vj0.w};
        const f32x4 vc1 = {vj1.x, vj1.y, vj1.z, vj1.w};
        f32x4 aR0 = __builtin_amdgcn_mfma_f32_16x16x32_bf16(A00, P2f[0], vc0, 0, 0, 0);
        aR0 = __builtin_amdgcn_mfma_f32_16x16x32_bf16(A01, P2f[1], aR0, 0, 0, 0);
        f32x4 aR1 = __builtin_amdgcn_mfma_f32_16x16x32_bf16(A10, P2f[0], vc1, 0, 0, 0);
        aR1 = __builtin_amdgcn_mfma_f32_16x16x32_bf16(A11, P2f[1], aR1, 0, 0, 0);
        aRp0 = aR0;
        aRp1 = aR1;

        // build next tile's A-frag (this wave's single task)
        if (n < 31) {
            float t[8];
#pragma unroll
            for (int e = 0; e < 8; ++e)
                t[e] = fmaxf(iv[e] - b2f((unsigned short)rawN[e]), 0.f);
            uint4 pk;
            pk.x = pk2(t[0], t[1]); pk.y = pk2(t[2], t[3]);
            pk.z = pk2(t[4], t[5]); pk.w = pk2(t[6], t[7]);
            AfL[nb][s_][h_][lane] = pk;
        }

        __syncthreads();  // publishes Hs[pb][*] (G2 next iter) and AfL[nb][*]
    }

    // ---- epilogue: deferred G2 for the final tile (pb=1, published above) ----
    {
        f32x4 aS0 = z4, aS1 = z4;
        const i32x8 h00 = ld32B(Hs[1][0] + m * 272 + 0   + 32 * q);
        const i32x8 h01 = ld32B(Hs[1][0] + m * 272 + 128 + 32 * q);
        const i32x8 h10 = ld32B(Hs[1][1] + m * 272 + 0   + 32 * q);
        const i32x8 h11 = ld32B(Hs[1][1] + m * 272 + 128 + 32 * q);
        aS0 = __builtin_amdgcn_mfma_scale_f32_16x16x128_f8f6f4(
            h00, W2f[0], aS0, 0, 0, 0, 127, 0, 127);
        aS0 = __builtin_amdgcn_mfma_scale_f32_16x16x128_f8f6f4(
            h01, W2f[1], aS0, 0, 0, 0, 127, 0, 127);
        aS1 = __builtin_amdgcn_mfma_scale_f32_16x16x128_f8f6f4(
            h10, W2f[0], aS1, 0, 0, 0, 127, 0, 127);
        aS1 = __builtin_amdgcn_mfma_scale_f32_16x16x128_f8f6f4(
            h11, W2f[1], aS1, 0, 0, 0, 127, 0, 127);
#pragma unroll
        for (int r = 0; r < 4; ++r) {
            const float e0 = EXP2(aS0[r]);
            num = fmaf(e0, aRp0[r], num);
            den += e0;
            const float e1 = EXP2(aS1[r]);
            num = fmaf(e1, aRp1[r], num);
            den += e1;
        }
    }

    // reduce the 4 quad-partials (lanes m, m+16, m+32, m+48)
    num += __shfl_xor(num, 16);
    num += __shfl_xor(num, 32);
    den += __shfl_xor(den, 16);
    den += __shfl_xor(den, 32);
    if (q == 0) out[i * 64 + 16 * w + m] = num / den;
}

extern "C" void kernel_launch(void* const* d_in, const int* in_sizes, int n_in,
                              void* d_out, int out_size, void* d_ws, size_t ws_size,
                              hipStream_t stream) {
    const float* x   = (const float*)d_in[0];
    const float* pos = (const float*)d_in[1];
    const float* Wq  = (const float*)d_in[2];
    const float* Wk  = (const float*)d_in[3];
    const float* Wv  = (const float*)d_in[4];
    const float* pW1 = (const float*)d_in[5];
    const float* pb1 = (const float*)d_in[6];
    const float* pW2 = (const float*)d_in[7];
    const float* pb2 = (const float*)d_in[8];
    const float* aW1 = (const float*)d_in[9];
    const float* ab1 = (const float*)d_in[10];
    const float* aW2 = (const float*)d_in[11];
    // d_in[12] = ab2: constant over j -> cancels in per-channel softmax, unused.

    char* ws = (char*)d_ws;
    unsigned short* bextf = (unsigned short*)(ws + BEXT_OFF);
    unsigned char*  aw2f8 = (unsigned char*)(ws + AW2F_OFF);
    unsigned short* pw2f  = (unsigned short*)(ws + PW2F_OFF);
    float*          cArr  = (float*)(ws + CARR_OFF);
    float*          aIa   = (float*)(ws + AI_OFF);
    unsigned short* aJa   = (unsigned short*)(ws + AJ_OFF);
    float*          vPTa  = (float*)(ws + VPT_OFF);
    float*          qaA   = (float*)(ws + QA_OFF);
    float*          knatA = (float*)(ws + KNAT_OFF);

    prep_all<<<1681, 256, 0, stream>>>(x, pos, Wq, Wk, Wv, pW1, pb1, pW2, pb2, aW1, ab1, aW2,
                                       bextf, aw2f8, pw2f, cArr, vPTa, aIa, aJa, qaA, knatA);
    ptl_main<<<NPTS, 256, 0, stream>>>(aIa, aJa, vPTa, bextf, aw2f8, pw2f, cArr, qaA, knatA,
                                       (float*)d_out);
}